// Round 1
// 4846.506 us; speedup vs baseline: 1.2012x; 1.2012x over previous
//
#include <hip/hip_runtime.h>
#include <math.h>

#define TSTEPS 1024
#define BATCH  512
#define HID    64
#define VOC    29
#define SOS    27

#define ENC_BLOCKS 256
#define DEC_BLOCKS 256
#define NTHREADS   512
#define WMAX       16

__device__ __forceinline__ float frcp(float x){ return __builtin_amdgcn_rcpf(x); }
__device__ __forceinline__ float sigmf(float x){ return frcp(1.0f + __expf(-x)); }
__device__ __forceinline__ float tanhfast(float x){ return 1.0f - 2.0f*frcp(1.0f + __expf(2.0f*x)); }

// ---------------- Encoder: cross-layer pipelined 2-layer LSTM, 2 rows/block ----------------
// (unchanged from previous round)
__global__ __attribute__((amdgpu_flat_work_group_size(NTHREADS,NTHREADS), amdgpu_waves_per_eu(2,2)))
void enc_kernel(const float* __restrict__ x,
                const float* __restrict__ Wih0, const float* __restrict__ Whh0,
                const float* __restrict__ bih0, const float* __restrict__ bhh0,
                const float* __restrict__ Wih1, const float* __restrict__ Whh1,
                const float* __restrict__ bih1, const float* __restrict__ bhh1,
                float* __restrict__ h1g, float* __restrict__ c1g)
{
  const int tid = threadIdx.x;
  const int b0  = blockIdx.x * 2;
  const bool g0 = tid < 256;
  const int  r  = g0 ? tid : (tid-256);

  __shared__ __align__(16) float xs[2][32];
  __shared__ __align__(16) float h0s[2][HID], h1s[2][HID];
  __shared__ __align__(16) float gA[2][256], gB[2][256];

  float wh[64], w2[64];
  if (g0){
    #pragma unroll
    for (int k=0;k<64;k++) wh[k] = Whh0[r*64+k];
    #pragma unroll
    for (int k=0;k<29;k++) w2[k] = Wih0[r*29+k];
    #pragma unroll
    for (int k=29;k<64;k++) w2[k] = 0.f;
  } else {
    #pragma unroll
    for (int k=0;k<64;k++){ wh[k] = Whh1[r*64+k]; w2[k] = Wih1[r*64+k]; }
  }
  const float bias = g0 ? (bih0[r]+bhh0[r]) : (bih1[r]+bhh1[r]);

  float creg = 0.f;
  if (tid < 128){ int u=tid>>6,k=tid&63; h0s[u][k]=0.f; h1s[u][k]=0.f; }

  const int pidx = tid - 448;
  const bool pf  = (pidx >= 0) && (pidx < 2*VOC);
  const int prow = pf ? (pidx/VOC) : 0;
  const int pcol = pf ? (pidx%VOC) : 0;
  if (pf) xs[prow][pcol] = x[(size_t)(b0+prow)*VOC + pcol];
  __syncthreads();

  for (int t=0;t<=TSTEPS;t++){
    float xv = 0.f;
    if (pf && t+1 < TSTEPS)
      xv = x[(size_t)(t+1)*BATCH*VOC + (size_t)(b0+prow)*VOC + pcol];

    if (g0){
      if (t < TSTEPS){
        #pragma unroll
        for (int u=0;u<2;u++){
          float a0=bias,a1=0.f,a2=0.f,a3=0.f;
          const float4* xv4 = (const float4*)xs[u];
          #pragma unroll
          for (int c=0;c<7;c++){
            float4 q=xv4[c];
            a0=fmaf(q.x,w2[4*c+0],a0); a1=fmaf(q.y,w2[4*c+1],a1);
            a2=fmaf(q.z,w2[4*c+2],a2); a3=fmaf(q.w,w2[4*c+3],a3);
          }
          a0=fmaf(xs[u][28],w2[28],a0);
          const float4* h4=(const float4*)h0s[u];
          #pragma unroll
          for (int c=0;c<16;c++){
            float4 q=h4[c];
            a0=fmaf(q.x,wh[4*c+0],a0); a1=fmaf(q.y,wh[4*c+1],a1);
            a2=fmaf(q.z,wh[4*c+2],a2); a3=fmaf(q.w,wh[4*c+3],a3);
          }
          gA[u][r]=(a0+a1)+(a2+a3);
        }
      }
    } else {
      if (t >= 1){
        #pragma unroll
        for (int u=0;u<2;u++){
          float a0=bias,a1=0.f,a2=0.f,a3=0.f;
          const float4* i4=(const float4*)h0s[u];
          const float4* h4=(const float4*)h1s[u];
          #pragma unroll
          for (int c=0;c<16;c++){
            float4 q=i4[c], w=h4[c];
            a0=fmaf(q.x,w2[4*c+0],a0); a1=fmaf(q.y,w2[4*c+1],a1);
            a2=fmaf(q.z,w2[4*c+2],a2); a3=fmaf(q.w,w2[4*c+3],a3);
            a0=fmaf(w.x,wh[4*c+0],a0); a1=fmaf(w.y,wh[4*c+1],a1);
            a2=fmaf(w.z,wh[4*c+2],a2); a3=fmaf(w.w,wh[4*c+3],a3);
          }
          gB[u][r]=(a0+a1)+(a2+a3);
        }
      }
    }
    __syncthreads();
    if (tid < 128){
      if (t < TSTEPS){
        int u=tid>>6,k=tid&63;
        float ig=gA[u][k],fg=gA[u][64+k],gg=gA[u][128+k],og=gA[u][192+k];
        float c=sigmf(fg)*creg + sigmf(ig)*tanhfast(gg);
        creg=c; h0s[u][k]=sigmf(og)*tanhfast(c);
      }
    } else if (tid < 384){
      if (t >= 1){
        int tt=tid-256,u=tt>>6,k=tt&63;
        float ig=gB[u][k],fg=gB[u][64+k],gg=gB[u][128+k],og=gB[u][192+k];
        float c=sigmf(fg)*creg + sigmf(ig)*tanhfast(gg);
        creg=c; h1s[u][k]=sigmf(og)*tanhfast(c);
      }
    }
    if (pf && t+1 < TSTEPS) xs[prow][pcol] = xv;
    __syncthreads();
  }

  if (tid >= 256 && tid < 384){
    int tt=tid-256,u=tt>>6,k=tt&63;
    h1g[(b0+u)*HID+k]=h1s[u][k];
    c1g[(b0+u)*HID+k]=creg;
  }
}

// ---------------- Decoder: windowed speculative execution, exact via rollback ----------------
// Per round rr: compute up to Wcur steps with the input mask FROZEN at the last verified
// union F, posting each step's local 2-row argmax mask to masks[rr&1][j][blk] (relaxed).
// One flag release + one poll per ROUND. Then read all masks once, compute true unions,
// validate the speculation, commit or rollback+recompute. Bit-exact vs per-step sync.
__global__ __attribute__((amdgpu_flat_work_group_size(NTHREADS,NTHREADS), amdgpu_waves_per_eu(2,2)))
void dec_kernel(const float* __restrict__ h1gp, const float* __restrict__ c1gp,
                const float* __restrict__ W1ih, const float* __restrict__ W1hh,
                const float* __restrict__ b1ih, const float* __restrict__ b1hh,
                const float* __restrict__ W2ih, const float* __restrict__ W2hh,
                const float* __restrict__ b2ih, const float* __restrict__ b2hh,
                const float* __restrict__ clsW, const float* __restrict__ clsb,
                float* __restrict__ out,
                unsigned* __restrict__ flags, unsigned* __restrict__ masks)
{
  const int tid  = threadIdx.x;
  const int r    = tid >> 1;
  const int p    = tid & 1;
  const int b0   = blockIdx.x * 2;
  const int blk  = blockIdx.x;

  __shared__ __align__(16) float clsW_s[VOC][68];
  __shared__ __align__(16) float clsb_s[32];
  __shared__ __align__(16) float gl[2][256];
  __shared__ __align__(16) float h1s[2][HID], h2s[2][HID];
  __shared__ __align__(16) float h1ck[2][HID], h2ck[2][HID];
  __shared__ unsigned u_lds[WMAX];

  for (int i=tid;i<VOC*HID;i+=NTHREADS) clsW_s[i/HID][i%HID] = clsW[i];
  if (tid<VOC) clsb_s[tid]=clsb[tid];

  // per-thread weight halves (forced resident)
  float w1h[32], w2i[32], w2h[32], wi1c[15];
  #pragma unroll
  for (int k=0;k<32;k++){
    w1h[k]=W1hh[r*HID+32*p+k];
    w2i[k]=W2ih[r*HID+32*p+k];
    w2h[k]=W2hh[r*HID+32*p+k];
  }
  const int cbase = p ? 15 : 0;
  const int cn    = p ? 14 : 15;
  #pragma unroll
  for (int j=0;j<15;j++) wi1c[j] = (j<cn) ? W1ih[r*VOC+cbase+j] : 0.f;
  const float biasg = p ? 0.f : (b1ih[r]+b1hh[r]);
  const float bias2 = p ? 0.f : (b2ih[r]+b2hh[r]);

  float c1reg=0.f, c2reg=0.f;
  if (tid<128){
    int u=tid>>6,k=tid&63;
    h1s[u][k]=h1gp[(b0+u)*HID+k];
    c1reg    =c1gp[(b0+u)*HID+k];
    h2s[u][k]=0.f;
  }
  __syncthreads();

  // initial hd1 partial: own half of W1hh . h1
  float hd1[2];
  #pragma unroll
  for (int u=0;u<2;u++){
    float a0=0.f,a1=0.f,a2=0.f,a3=0.f;
    const float4* h4=(const float4*)(h1s[u]+32*p);
    #pragma unroll
    for (int c=0;c<8;c++){
      float4 q=h4[c];
      a0=fmaf(q.x,w1h[4*c+0],a0); a1=fmaf(q.y,w1h[4*c+1],a1);
      a2=fmaf(q.z,w1h[4*c+2],a2); a3=fmaf(q.w,w1h[4*c+3],a3);
    }
    hd1[u]=(a0+a1)+(a2+a3);
  }

  unsigned F = 1u<<SOS;  // verified union mask feeding the current frontier step
  int f = 0;             // frontier: first step of the current window
  unsigned rr = 0;       // round counter (uniform across blocks)
  int Wcur = 4;          // adaptive window size

  while (f < TSTEPS){
    const int Wr = (TSTEPS - f < Wcur) ? (TSTEPS - f) : Wcur;

    // ---- checkpoint round-start state ----
    const float c1ck=c1reg, c2ck=c2reg, hd10=hd1[0], hd11=hd1[1];
    if (tid<128){ int u=tid>>6,k=tid&63; h1ck[u][k]=h1s[u][k]; h2ck[u][k]=h2s[u][k]; }

    // round-constant gate1 input term (frozen mask F) — identical summation order as before
    float it0 = biasg;
    #pragma unroll
    for (int jj=0;jj<15;jj++) it0 += ((F>>(cbase+jj))&1u) ? wi1c[jj] : 0.f;

    unsigned* __restrict__ mrow = masks + (rr&1u)*(WMAX*256);

    // ---- speculative window compute ----
    for (int j=0;j<Wr;j++){
      // gate1 = frozen input term + recurrent partial
      #pragma unroll
      for (int u=0;u<2;u++){
        float v = it0 + hd1[u];
        v += __shfl_xor(v,1);
        if (!p) gl[u][r] = v;
      }
      __syncthreads();
      if (tid<128){
        int u=tid>>6,k=tid&63;
        float ig=gl[u][k],fg=gl[u][64+k],gg=gl[u][128+k],og=gl[u][192+k];
        float c=sigmf(fg)*c1reg+sigmf(ig)*tanhfast(gg);
        c1reg=c; h1s[u][k]=sigmf(og)*tanhfast(c);
      }
      __syncthreads();
      // gate2
      #pragma unroll
      for (int u=0;u<2;u++){
        float a0=bias2,a1=0.f,a2=0.f,a3=0.f;
        const float4* i4=(const float4*)(h1s[u]+32*p);
        const float4* h4=(const float4*)(h2s[u]+32*p);
        #pragma unroll
        for (int c=0;c<8;c++){
          float4 q=i4[c], w=h4[c];
          a0=fmaf(q.x,w2i[4*c+0],a0); a1=fmaf(q.y,w2i[4*c+1],a1);
          a2=fmaf(q.z,w2i[4*c+2],a2); a3=fmaf(q.w,w2i[4*c+3],a3);
          a0=fmaf(w.x,w2h[4*c+0],a0); a1=fmaf(w.y,w2h[4*c+1],a1);
          a2=fmaf(w.z,w2h[4*c+2],a2); a3=fmaf(w.w,w2h[4*c+3],a3);
        }
        float v=(a0+a1)+(a2+a3);
        v += __shfl_xor(v,1);
        if (!p) gl[u][r]=v;
      }
      __syncthreads();
      if (tid<128){
        int u=tid>>6,k=tid&63;
        float ig=gl[u][k],fg=gl[u][64+k],gg=gl[u][128+k],og=gl[u][192+k];
        float c=sigmf(fg)*c2reg+sigmf(ig)*tanhfast(gg);
        c2reg=c; h2s[u][k]=sigmf(og)*tanhfast(c);
      }
      __syncthreads();
      // classifier + argmax + post local mask (wave 0)
      if (tid<64){
        const int s = f + j;
        int row=tid>>5, v=tid&31;
        float pv = -INFINITY;
        if (v<VOC){
          float a0=clsb_s[v],a1=0.f,a2=0.f,a3=0.f;
          const float4* h4=(const float4*)h2s[row];
          #pragma unroll
          for (int c=0;c<16;c++){
            float4 q=h4[c];
            a0=fmaf(q.x,clsW_s[v][4*c+0],a0); a1=fmaf(q.y,clsW_s[v][4*c+1],a1);
            a2=fmaf(q.z,clsW_s[v][4*c+2],a2); a3=fmaf(q.w,clsW_s[v][4*c+3],a3);
          }
          pv=(a0+a1)+(a2+a3);
          out[((size_t)s*BATCH + (size_t)(b0+row))*VOC + v]=pv;
        }
        int ix=v;
        #pragma unroll
        for (int off=16; off>0; off>>=1){
          float ov=__shfl_xor(pv,off);
          int   oi=__shfl_xor(ix,off);
          if (ov>pv || (ov==pv && oi<ix)){ pv=ov; ix=oi; }
        }
        unsigned bit = 1u<<ix;
        unsigned mb  = bit | __shfl_xor(bit,32);
        if (tid==0){
          __hip_atomic_store(&mrow[j*256+blk], mb, __ATOMIC_RELAXED, __HIP_MEMORY_SCOPE_AGENT);
          if (j==Wr-1)  // last step of window: publish round completion (release covers mask stores)
            __hip_atomic_store(&flags[blk], rr+1u, __ATOMIC_RELEASE, __HIP_MEMORY_SCOPE_AGENT);
        }
      }
      // hd1 for next step (all threads; overlaps wave0's classifier)
      #pragma unroll
      for (int u=0;u<2;u++){
        float a0=0.f,a1=0.f,a2=0.f,a3=0.f;
        const float4* h4=(const float4*)(h1s[u]+32*p);
        #pragma unroll
        for (int c=0;c<8;c++){
          float4 q=h4[c];
          a0=fmaf(q.x,w1h[4*c+0],a0); a1=fmaf(q.y,w1h[4*c+1],a1);
          a2=fmaf(q.z,w1h[4*c+2],a2); a3=fmaf(q.w,w1h[4*c+3],a3);
        }
        hd1[u]=(a0+a1)+(a2+a3);
      }
    }

    // ---- one poll per round: wait for all 256 blocks' round flags ----
    if (tid<64){
      const unsigned tgt = rr+1u;
      for(;;){
        unsigned a=__hip_atomic_load(&flags[tid    ],__ATOMIC_RELAXED,__HIP_MEMORY_SCOPE_AGENT);
        unsigned b=__hip_atomic_load(&flags[tid+ 64],__ATOMIC_RELAXED,__HIP_MEMORY_SCOPE_AGENT);
        unsigned c=__hip_atomic_load(&flags[tid+128],__ATOMIC_RELAXED,__HIP_MEMORY_SCOPE_AGENT);
        unsigned d=__hip_atomic_load(&flags[tid+192],__ATOMIC_RELAXED,__HIP_MEMORY_SCOPE_AGENT);
        bool ok = (a>=tgt)&&(b>=tgt)&&(c>=tgt)&&(d>=tgt);
        if (__ballot(ok)==~0ull) break;
      }
      __threadfence();
    }
    __syncthreads();

    // ---- read all posted masks once, compute per-step unions ----
    {
      const int j = tid>>5, sub = tid&31;
      if (j < Wr){
        unsigned* mp = mrow + j*256;
        unsigned um=0;
        #pragma unroll
        for (int q=0;q<8;q++)
          um |= __hip_atomic_load(&mp[q*32+sub],__ATOMIC_RELAXED,__HIP_MEMORY_SCOPE_AGENT);
        um |= __shfl_xor(um,1); um |= __shfl_xor(um,2);
        um |= __shfl_xor(um,4); um |= __shfl_xor(um,8); um |= __shfl_xor(um,16);
        if (sub==0) u_lds[j]=um;
      }
    }
    __syncthreads();

    // ---- validate speculation (identical integer decision in every block) ----
    int jstar = Wr;
    for (int jj=1;jj<Wr;jj++){ if (u_lds[jj-1]!=F){ jstar=jj; break; } }

    if (jstar==Wr){
      // whole window valid; state, outputs and posts are all correct
      F = u_lds[Wr-1];
      f += Wr; rr++;
      Wcur = (2*Wcur>WMAX)?WMAX:2*Wcur;
    } else {
      // steps f..f+jstar-1 had correct inputs (outputs/posts correct); state beyond is
      // corrupted — restore checkpoint and recompute jstar steps (no classifier needed)
      c1reg=c1ck; c2reg=c2ck; hd1[0]=hd10; hd1[1]=hd11;
      if (tid<128){ int u=tid>>6,k=tid&63; h1s[u][k]=h1ck[u][k]; h2s[u][k]=h2ck[u][k]; }
      for (int j2=0;j2<jstar;j2++){
        #pragma unroll
        for (int u=0;u<2;u++){
          float v = it0 + hd1[u];
          v += __shfl_xor(v,1);
          if (!p) gl[u][r] = v;
        }
        __syncthreads();
        if (tid<128){
          int u=tid>>6,k=tid&63;
          float ig=gl[u][k],fg=gl[u][64+k],gg=gl[u][128+k],og=gl[u][192+k];
          float c=sigmf(fg)*c1reg+sigmf(ig)*tanhfast(gg);
          c1reg=c; h1s[u][k]=sigmf(og)*tanhfast(c);
        }
        __syncthreads();
        #pragma unroll
        for (int u=0;u<2;u++){
          float a0=bias2,a1=0.f,a2=0.f,a3=0.f;
          const float4* i4=(const float4*)(h1s[u]+32*p);
          const float4* h4=(const float4*)(h2s[u]+32*p);
          #pragma unroll
          for (int c=0;c<8;c++){
            float4 q=i4[c], w=h4[c];
            a0=fmaf(q.x,w2i[4*c+0],a0); a1=fmaf(q.y,w2i[4*c+1],a1);
            a2=fmaf(q.z,w2i[4*c+2],a2); a3=fmaf(q.w,w2i[4*c+3],a3);
            a0=fmaf(w.x,w2h[4*c+0],a0); a1=fmaf(w.y,w2h[4*c+1],a1);
            a2=fmaf(w.z,w2h[4*c+2],a2); a3=fmaf(w.w,w2h[4*c+3],a3);
          }
          float v=(a0+a1)+(a2+a3);
          v += __shfl_xor(v,1);
          if (!p) gl[u][r]=v;
        }
        __syncthreads();
        if (tid<128){
          int u=tid>>6,k=tid&63;
          float ig=gl[u][k],fg=gl[u][64+k],gg=gl[u][128+k],og=gl[u][192+k];
          float c=sigmf(fg)*c2reg+sigmf(ig)*tanhfast(gg);
          c2reg=c; h2s[u][k]=sigmf(og)*tanhfast(c);
        }
        __syncthreads();
        #pragma unroll
        for (int u=0;u<2;u++){
          float a0=0.f,a1=0.f,a2=0.f,a3=0.f;
          const float4* h4=(const float4*)(h1s[u]+32*p);
          #pragma unroll
          for (int c=0;c<8;c++){
            float4 q=h4[c];
            a0=fmaf(q.x,w1h[4*c+0],a0); a1=fmaf(q.y,w1h[4*c+1],a1);
            a2=fmaf(q.z,w1h[4*c+2],a2); a3=fmaf(q.w,w1h[4*c+3],a3);
          }
          hd1[u]=(a0+a1)+(a2+a3);
        }
      }
      F = u_lds[jstar-1];
      f += jstar; rr++;
      Wcur = jstar;   // shrink toward per-step sync while the mask is churning
    }
  }
}

extern "C" void kernel_launch(void* const* d_in, const int* in_sizes, int n_in,
                              void* d_out, int out_size, void* d_ws, size_t ws_size,
                              hipStream_t stream)
{
  const float* x     = (const float*)d_in[0];
  const float* eWih0 = (const float*)d_in[1];
  const float* eWhh0 = (const float*)d_in[2];
  const float* ebih0 = (const float*)d_in[3];
  const float* ebhh0 = (const float*)d_in[4];
  const float* eWih1 = (const float*)d_in[5];
  const float* eWhh1 = (const float*)d_in[6];
  const float* ebih1 = (const float*)d_in[7];
  const float* ebhh1 = (const float*)d_in[8];
  const float* d1Wih = (const float*)d_in[9];
  const float* d1Whh = (const float*)d_in[10];
  const float* d1bih = (const float*)d_in[11];
  const float* d1bhh = (const float*)d_in[12];
  const float* d2Wih = (const float*)d_in[13];
  const float* d2Whh = (const float*)d_in[14];
  const float* d2bih = (const float*)d_in[15];
  const float* d2bhh = (const float*)d_in[16];
  const float* clsW  = (const float*)d_in[17];
  const float* clsb  = (const float*)d_in[18];
  float* out = (float*)d_out;

  float* h1g = (float*)d_ws;
  float* c1g = h1g + BATCH*HID;
  unsigned* flags = (unsigned*)(c1g + BATCH*HID);      // 256 u32
  unsigned* masks = flags + 256;                       // [2][WMAX][256] u32

  hipMemsetAsync(flags, 0, 256*sizeof(unsigned), stream);

  enc_kernel<<<ENC_BLOCKS, NTHREADS, 0, stream>>>(
      x, eWih0,eWhh0,ebih0,ebhh0, eWih1,eWhh1,ebih1,ebhh1, h1g,c1g);

  void* args[] = { (void*)&h1g, (void*)&c1g,
                   (void*)&d1Wih,(void*)&d1Whh,(void*)&d1bih,(void*)&d1bhh,
                   (void*)&d2Wih,(void*)&d2Whh,(void*)&d2bih,(void*)&d2bhh,
                   (void*)&clsW,(void*)&clsb,(void*)&out,
                   (void*)&flags,(void*)&masks };
  hipLaunchCooperativeKernel((void*)dec_kernel, dim3(DEC_BLOCKS), dim3(NTHREADS),
                             args, 0, stream);
}